// Round 1
// baseline (193.607 us; speedup 1.0000x reference)
//
#include <hip/hip_runtime.h>
#include <hip/hip_bf16.h>

// Problem constants (B,T,C,HS) = (8,4096,1024,64)
#define BB 8
#define TT 4096
#define CC 1024
#define HS 64

typedef __attribute__((ext_vector_type(8))) __bf16 bf16x8;
typedef __attribute__((ext_vector_type(4))) __bf16 bf16x4;
typedef __attribute__((ext_vector_type(4))) float f32x4;

// ---------------------------------------------------------------------------
// Kernel 0: W prep.  Wt[192][1024] bf16 = [Wq^T * 0.125 | Wk^T | Wv^T]
// ---------------------------------------------------------------------------
__global__ __launch_bounds__(256) void wprep_kernel(
    const float* __restrict__ Wq, const float* __restrict__ Wk,
    const float* __restrict__ Wv, __bf16* __restrict__ Wt)
{
    int i = blockIdx.x * 256 + threadIdx.x;      // 0 .. 192*1024-1
    int dr = i >> 10;                            // 0..191
    int c  = i & 1023;                           // 0..1023
    int m  = dr >> 6;                            // 0=q,1=k,2=v
    int d  = dr & 63;
    const float* src = (m == 0) ? Wq : ((m == 1) ? Wk : Wv);
    float v = src[(long)c * HS + d];
    if (m == 0) v *= 0.125f;                     // fold 1/sqrt(HS) into Wq
    Wt[i] = (__bf16)v;
}

// ---------------------------------------------------------------------------
// Kernel 1: QKV projection + RoPE.  One block = 64 token rows, 4 waves x 16.
// acc frags: nf 0..3 = Q dims, 4..7 = K dims, 8..11 = V dims.
// ---------------------------------------------------------------------------
__global__ __launch_bounds__(256) void qkv_rope_kernel(
    const float* __restrict__ x,     // [B*T][C]
    const float* __restrict__ cosT,  // [T][32]
    const float* __restrict__ sinT,  // [T][32]
    const __bf16* __restrict__ Wt,   // [192][1024]
    __bf16* __restrict__ Qo, __bf16* __restrict__ Ko, __bf16* __restrict__ Vo)
{
    __shared__ __bf16 xs[64][72];
    __shared__ __bf16 Wl[192][72];

    const int tid  = threadIdx.x;
    const int lane = tid & 63;
    const int w    = tid >> 6;
    const int col  = lane & 15;
    const int grp  = lane >> 4;
    const long rowbase = (long)blockIdx.x * 64;

    f32x4 acc[12];
#pragma unroll
    for (int i = 0; i < 12; i++) acc[i] = 0.0f;

    for (int ck = 0; ck < CC; ck += 64) {
        // stage x tile 64x64 fp32 -> bf16 LDS (row-major)
        {
            int r = tid >> 2, c0 = (tid & 3) * 16;
            const float4* src = (const float4*)(x + (rowbase + r) * (long)CC + ck + c0);
#pragma unroll
            for (int i = 0; i < 4; i++) {
                float4 v = src[i];
                bf16x4 t;
                t[0] = (__bf16)v.x; t[1] = (__bf16)v.y;
                t[2] = (__bf16)v.z; t[3] = (__bf16)v.w;
                *(bf16x4*)&xs[r][c0 + i * 4] = t;
            }
        }
        // stage Wt chunk 192x64 bf16 -> LDS
        {
#pragma unroll
            for (int i = 0; i < 6; i++) {
                int u = i * 256 + tid;           // 0..1535 units of 8 cols
                int dr = u >> 3, cu = (u & 7) * 8;
                bf16x8 v = *(const bf16x8*)(Wt + (long)dr * CC + ck + cu);
                *(bf16x8*)&Wl[dr][cu] = v;
            }
        }
        __syncthreads();
#pragma unroll
        for (int s = 0; s < 2; s++) {
            bf16x8 a = *(const bf16x8*)&xs[w * 16 + col][s * 32 + grp * 8];
#pragma unroll
            for (int nf = 0; nf < 12; nf++) {
                bf16x8 b = *(const bf16x8*)&Wl[nf * 16 + col][s * 32 + grp * 8];
                acc[nf] = __builtin_amdgcn_mfma_f32_16x16x32_bf16(a, b, acc[nf], 0, 0, 0);
            }
        }
        __syncthreads();
    }

    // RoPE on Q/K frags + store bf16
#pragma unroll
    for (int r = 0; r < 4; r++) {
        long grow = rowbase + w * 16 + grp * 4 + r;  // flat token row
        int t = (int)(grow & (TT - 1));              // token within sequence
        const float* cp = cosT + (long)t * 32;
        const float* sp = sinT + (long)t * 32;
#pragma unroll
        for (int nf = 0; nf < 4; nf++) {
            int ii = nf * 8 + (col >> 1);
            float cs = cp[ii], sn = sp[ii];
            float sgn_sn = (col & 1) ? sn : -sn;
            // q
            float qv = acc[nf][r];
            float qp = __shfl_xor(qv, 1);
            float qo = qv * cs + qp * sgn_sn;
            // k
            float kv = acc[nf + 4][r];
            float kp = __shfl_xor(kv, 1);
            float ko = kv * cs + kp * sgn_sn;
            // v
            float vv = acc[nf + 8][r];
            long base = grow * HS + nf * 16 + col;
            Qo[base] = (__bf16)qo;
            Ko[base] = (__bf16)ko;
            Vo[base] = (__bf16)vv;
        }
    }
}

// ---------------------------------------------------------------------------
// Kernel 2: causal flash attention.  grid (64 q-tiles, 8 batches), 256 thr.
// Wave w owns q rows [qi*64 + w*16, +16).  KV tile = 64.
// ---------------------------------------------------------------------------
__global__ __launch_bounds__(256) void attn_kernel(
    const __bf16* __restrict__ Q, const __bf16* __restrict__ K,
    const __bf16* __restrict__ V, float* __restrict__ O)
{
    __shared__ __bf16 Kl[64][72];       // [kv][dim]
    __shared__ __bf16 Vt[64][72];       // [dim][kv]  (transposed)
    __shared__ __bf16 Pl[4][16][72];    // per-wave P [q_local][kv]

    const int tid  = threadIdx.x;
    const int lane = tid & 63;
    const int w    = tid >> 6;
    const int col  = lane & 15;
    const int grp  = lane >> 4;
    const int qi   = blockIdx.x;
    const int b    = blockIdx.y;
    const long qbase  = (long)b * TT + (long)qi * 64;
    const long kvbase = (long)b * TT;

    // Q fragments (A operand), row = w*16+col, dims s*32 + grp*8 ..+7
    bf16x8 qa[2];
#pragma unroll
    for (int s = 0; s < 2; s++)
        qa[s] = *(const bf16x8*)(Q + (qbase + w * 16 + col) * HS + s * 32 + grp * 8);

    f32x4 o[4];
#pragma unroll
    for (int nf = 0; nf < 4; nf++) o[nf] = 0.0f;
    float mrow[4], lrow[4];
#pragma unroll
    for (int r = 0; r < 4; r++) { mrow[r] = -3e38f; lrow[r] = 0.0f; }

    for (int j = 0; j <= qi; ++j) {
        // ---- stage K (row-major) and V (transposed) bf16 tiles ----
        {
            int r = tid >> 2, c0 = (tid & 3) * 16;
            const __bf16* ksrc = K + (kvbase + j * 64 + r) * HS + c0;
            bf16x8 k0 = *(const bf16x8*)(ksrc);
            bf16x8 k1 = *(const bf16x8*)(ksrc + 8);
            *(bf16x8*)&Kl[r][c0]     = k0;
            *(bf16x8*)&Kl[r][c0 + 8] = k1;
            const __bf16* vsrc = V + (kvbase + j * 64 + r) * HS + c0;
            bf16x8 v0 = *(const bf16x8*)(vsrc);
            bf16x8 v1 = *(const bf16x8*)(vsrc + 8);
#pragma unroll
            for (int e = 0; e < 8; e++) {
                Vt[c0 + e][r]     = v0[e];
                Vt[c0 + 8 + e][r] = v1[e];
            }
        }
        __syncthreads();

        // ---- S = Q K^T  (16 q rows x 64 kv per wave) ----
        f32x4 sf[4];
#pragma unroll
        for (int nf = 0; nf < 4; nf++) sf[nf] = 0.0f;
#pragma unroll
        for (int s = 0; s < 2; s++) {
#pragma unroll
            for (int nf = 0; nf < 4; nf++) {
                bf16x8 bk = *(const bf16x8*)&Kl[nf * 16 + col][s * 32 + grp * 8];
                sf[nf] = __builtin_amdgcn_mfma_f32_16x16x32_bf16(qa[s], bk, sf[nf], 0, 0, 0);
            }
        }
        // ---- causal mask on diagonal tile ----
        if (j == qi) {
#pragma unroll
            for (int nf = 0; nf < 4; nf++) {
                int kvg = nf * 16 + col;
#pragma unroll
                for (int r = 0; r < 4; r++) {
                    int qg = w * 16 + grp * 4 + r;
                    if (kvg > qg) sf[nf][r] = -3e38f;
                }
            }
        }
        // ---- online softmax ----
        float alpha[4];
#pragma unroll
        for (int r = 0; r < 4; r++) {
            float mx = fmaxf(fmaxf(sf[0][r], sf[1][r]), fmaxf(sf[2][r], sf[3][r]));
            mx = fmaxf(mx, __shfl_xor(mx, 1));
            mx = fmaxf(mx, __shfl_xor(mx, 2));
            mx = fmaxf(mx, __shfl_xor(mx, 4));
            mx = fmaxf(mx, __shfl_xor(mx, 8));
            float nm = fmaxf(mrow[r], mx);
            alpha[r] = __expf(mrow[r] - nm);
            mrow[r] = nm;
        }
        float ts[4] = {0.f, 0.f, 0.f, 0.f};
#pragma unroll
        for (int nf = 0; nf < 4; nf++) {
#pragma unroll
            for (int r = 0; r < 4; r++) {
                float p = __expf(sf[nf][r] - mrow[r]);
                sf[nf][r] = p;
                ts[r] += p;
            }
        }
#pragma unroll
        for (int r = 0; r < 4; r++) {
            float s = ts[r];
            s += __shfl_xor(s, 1);
            s += __shfl_xor(s, 2);
            s += __shfl_xor(s, 4);
            s += __shfl_xor(s, 8);
            lrow[r] = lrow[r] * alpha[r] + s;
#pragma unroll
            for (int nf = 0; nf < 4; nf++) o[nf][r] *= alpha[r];
        }
        // ---- P -> LDS (bf16) in A-fragment-friendly layout ----
#pragma unroll
        for (int nf = 0; nf < 4; nf++)
#pragma unroll
            for (int r = 0; r < 4; r++)
                Pl[w][grp * 4 + r][nf * 16 + col] = (__bf16)sf[nf][r];
        __syncthreads();

        // ---- O += P V ----
#pragma unroll
        for (int s = 0; s < 2; s++) {
            bf16x8 pa = *(const bf16x8*)&Pl[w][col][s * 32 + grp * 8];
#pragma unroll
            for (int nf = 0; nf < 4; nf++) {
                bf16x8 bv = *(const bf16x8*)&Vt[nf * 16 + col][s * 32 + grp * 8];
                o[nf] = __builtin_amdgcn_mfma_f32_16x16x32_bf16(pa, bv, o[nf], 0, 0, 0);
            }
        }
        __syncthreads();
    }

    // ---- epilogue: normalize and store fp32 ----
#pragma unroll
    for (int nf = 0; nf < 4; nf++) {
#pragma unroll
        for (int r = 0; r < 4; r++) {
            long row = qbase + w * 16 + grp * 4 + r;
            O[row * HS + nf * 16 + col] = o[nf][r] / lrow[r];
        }
    }
}

// ---------------------------------------------------------------------------
extern "C" void kernel_launch(void* const* d_in, const int* in_sizes, int n_in,
                              void* d_out, int out_size, void* d_ws, size_t ws_size,
                              hipStream_t stream)
{
    const float* x    = (const float*)d_in[0];
    const float* cosT = (const float*)d_in[1];
    const float* sinT = (const float*)d_in[2];
    const float* Wq   = (const float*)d_in[3];
    const float* Wk   = (const float*)d_in[4];
    const float* Wv   = (const float*)d_in[5];
    float* out = (float*)d_out;

    // ws layout (needs ~13 MB): Q | K | V (bf16, B*T*HS each) | Wt (192x1024 bf16)
    __bf16* Qb = (__bf16*)d_ws;
    __bf16* Kb = Qb + (size_t)BB * TT * HS;
    __bf16* Vb = Kb + (size_t)BB * TT * HS;
    __bf16* Wt = Vb + (size_t)BB * TT * HS;

    wprep_kernel<<<(192 * 1024) / 256, 256, 0, stream>>>(Wq, Wk, Wv, Wt);
    qkv_rope_kernel<<<(BB * TT) / 64, 256, 0, stream>>>(x, cosT, sinT, Wt, Qb, Kb, Vb);
    attn_kernel<<<dim3(TT / 64, BB), 256, 0, stream>>>(Qb, Kb, Vb, out);
}

// Round 2
// 154.822 us; speedup vs baseline: 1.2505x; 1.2505x over previous
//
#include <hip/hip_runtime.h>
#include <hip/hip_bf16.h>

// Problem constants (B,T,C,HS) = (8,4096,1024,64)
#define BB 8
#define TT 4096
#define CC 1024
#define HS 64

typedef __attribute__((ext_vector_type(8))) __bf16 bf16x8;
typedef __attribute__((ext_vector_type(4))) __bf16 bf16x4;
typedef __attribute__((ext_vector_type(4))) float f32x4;

static __device__ __forceinline__ unsigned pack_bf16(float a, float b) {
    unsigned short ua = __builtin_bit_cast(unsigned short, (__bf16)a);
    unsigned short ub = __builtin_bit_cast(unsigned short, (__bf16)b);
    return (unsigned)ua | ((unsigned)ub << 16);
}

// ---------------------------------------------------------------------------
// Kernel 0: W prep.  Wt[192][1024] bf16 = [Wq^T * 0.125 | Wk^T | Wv^T]
// ---------------------------------------------------------------------------
__global__ __launch_bounds__(256) void wprep_kernel(
    const float* __restrict__ Wq, const float* __restrict__ Wk,
    const float* __restrict__ Wv, __bf16* __restrict__ Wt)
{
    int i = blockIdx.x * 256 + threadIdx.x;
    int dr = i >> 10;
    int c  = i & 1023;
    int m  = dr >> 6;
    int d  = dr & 63;
    const float* src = (m == 0) ? Wq : ((m == 1) ? Wk : Wv);
    float v = src[(long)c * HS + d];
    if (m == 0) v *= 0.125f;                     // fold 1/sqrt(HS) into Wq
    Wt[i] = (__bf16)v;
}

// ---------------------------------------------------------------------------
// Kernel 1: QKV projection + RoPE.  One block = 64 token rows, 4 waves x 16.
// Q,K stored row-major [t][d]; V stored TRANSPOSED Vt[b*64+d][t] (via LDS).
// ---------------------------------------------------------------------------
__global__ __launch_bounds__(256) void qkv_rope_kernel(
    const float* __restrict__ x,     // [B*T][C]
    const float* __restrict__ cosT,  // [T][32]
    const float* __restrict__ sinT,  // [T][32]
    const __bf16* __restrict__ Wt,   // [192][1024]
    __bf16* __restrict__ Qo, __bf16* __restrict__ Ko, __bf16* __restrict__ Vo)
{
    __shared__ __bf16 xs[64][72];
    __shared__ __bf16 Wl[192][72];

    const int tid  = threadIdx.x;
    const int lane = tid & 63;
    const int w    = tid >> 6;
    const int col  = lane & 15;
    const int grp  = lane >> 4;
    const long rowbase = (long)blockIdx.x * 64;

    f32x4 acc[12];
#pragma unroll
    for (int i = 0; i < 12; i++) acc[i] = 0.0f;

    for (int ck = 0; ck < CC; ck += 64) {
        {
            int r = tid >> 2, c0 = (tid & 3) * 16;
            const float4* src = (const float4*)(x + (rowbase + r) * (long)CC + ck + c0);
#pragma unroll
            for (int i = 0; i < 4; i++) {
                float4 v = src[i];
                bf16x4 t;
                t[0] = (__bf16)v.x; t[1] = (__bf16)v.y;
                t[2] = (__bf16)v.z; t[3] = (__bf16)v.w;
                *(bf16x4*)&xs[r][c0 + i * 4] = t;
            }
        }
        {
#pragma unroll
            for (int i = 0; i < 6; i++) {
                int u = i * 256 + tid;
                int dr = u >> 3, cu = (u & 7) * 8;
                bf16x8 v = *(const bf16x8*)(Wt + (long)dr * CC + ck + cu);
                *(bf16x8*)&Wl[dr][cu] = v;
            }
        }
        __syncthreads();
#pragma unroll
        for (int s = 0; s < 2; s++) {
            bf16x8 a = *(const bf16x8*)&xs[w * 16 + col][s * 32 + grp * 8];
#pragma unroll
            for (int nf = 0; nf < 12; nf++) {
                bf16x8 b = *(const bf16x8*)&Wl[nf * 16 + col][s * 32 + grp * 8];
                acc[nf] = __builtin_amdgcn_mfma_f32_16x16x32_bf16(a, b, acc[nf], 0, 0, 0);
            }
        }
        __syncthreads();
    }

    // RoPE on Q/K + store; V goes into xs (reused) for transposed store
#pragma unroll
    for (int r = 0; r < 4; r++) {
        long grow = rowbase + w * 16 + grp * 4 + r;
        int t = (int)(grow & (TT - 1));
        const float* cp = cosT + (long)t * 32;
        const float* sp = sinT + (long)t * 32;
#pragma unroll
        for (int nf = 0; nf < 4; nf++) {
            int ii = nf * 8 + (col >> 1);
            float cs = cp[ii], sn = sp[ii];
            float sgn_sn = (col & 1) ? sn : -sn;
            float qv = acc[nf][r];
            float qp = __shfl_xor(qv, 1);
            float qo = qv * cs + qp * sgn_sn;
            float kv = acc[nf + 4][r];
            float kp = __shfl_xor(kv, 1);
            float ko = kv * cs + kp * sgn_sn;
            long base = grow * HS + nf * 16 + col;
            Qo[base] = (__bf16)qo;
            Ko[base] = (__bf16)ko;
            xs[nf * 16 + col][w * 16 + grp * 4 + r] = (__bf16)acc[nf + 8][r];
        }
    }
    __syncthreads();
    // coalesced transposed V store: Vt[b*64+d][t0 .. t0+63]
    {
        int d = tid >> 2, seg = tid & 3;
        int b  = (int)(rowbase >> 12);
        int t0 = (int)(rowbase & (TT - 1));
        bf16x8 v0 = *(const bf16x8*)&xs[d][seg * 16];
        bf16x8 v1 = *(const bf16x8*)&xs[d][seg * 16 + 8];
        __bf16* dst = Vo + ((size_t)b * 64 + d) * TT + t0 + seg * 16;
        *(bf16x8*)dst = v0;
        *(bf16x8*)(dst + 8) = v1;
    }
}

// ---------------------------------------------------------------------------
// Kernel 2: barrier-free causal flash attention.
// 512 blocks x 256 thr; wave = independent 16 q-rows. b = XCD-pinned batch.
// S^T = mfma(K rows, Q rows); O^T = mfma(Vt rows, P rows).
// P^T -> P-rows via wave-private swizzled LDS bounce (no __syncthreads).
// ---------------------------------------------------------------------------
__global__ __launch_bounds__(256) void attn_kernel(
    const __bf16* __restrict__ Q, const __bf16* __restrict__ K,
    const __bf16* __restrict__ Vt, float* __restrict__ O)
{
    __shared__ __align__(16) unsigned char plds[4][2048];
    __shared__ float elds[4][16 * 72];

    const int tid  = threadIdx.x;
    const int lane = tid & 63;
    const int col  = lane & 15;
    const int g    = lane >> 4;
    const int w    = tid >> 6;

    const int n  = blockIdx.x;
    const int b  = n & 7;                 // batch pinned to XCD n%8
    const int gg = n >> 3;
    const int qt = (gg < 32) ? gg : 95 - gg;   // pair heavy/light q-tiles per CU
    const int nj = qt + 1;

    const size_t qrow = (size_t)b * TT + qt * 64 + w * 16 + col;
    bf16x8 qb[2];
#pragma unroll
    for (int s = 0; s < 2; s++)
        qb[s] = *(const bf16x8*)(Q + qrow * HS + s * 32 + g * 8);

    const __bf16* Kp = K + ((size_t)b * TT + col) * HS + g * 8;
    const __bf16* Vp = Vt + ((size_t)b * 64 + col) * TT + g * 8;

    f32x4 acc[4];
#pragma unroll
    for (int i = 0; i < 4; i++) acc[i] = 0.f;
    float mrun = -3e38f, lrun = 0.f;

    bf16x8 KA[8], KB[8], VF[8];
    unsigned char* pbase = plds[w] + col * 128;
    const int sw = col & 7;

    auto issueK = [&](int j, bf16x8 (&Kf)[8]) {
        const __bf16* p = Kp + (size_t)j * (64 * HS);
#pragma unroll
        for (int nf = 0; nf < 4; nf++)
#pragma unroll
            for (int s = 0; s < 2; s++)
                Kf[nf * 2 + s] = *(const bf16x8*)(p + nf * 16 * HS + s * 32);
    };
    auto issueV = [&](int j) {
        const __bf16* p = Vp + j * 64;
#pragma unroll
        for (int nf = 0; nf < 4; nf++)
#pragma unroll
            for (int s = 0; s < 2; s++)
                VF[nf * 2 + s] = *(const bf16x8*)(p + (size_t)nf * 16 * TT + s * 32);
    };

    auto tile = [&](const bf16x8 (&Kf)[8], bool diag) {
        f32x4 sf[4];
#pragma unroll
        for (int i = 0; i < 4; i++) sf[i] = 0.f;
#pragma unroll
        for (int s = 0; s < 2; s++)
#pragma unroll
            for (int nf = 0; nf < 4; nf++)
                sf[nf] = __builtin_amdgcn_mfma_f32_16x16x32_bf16(Kf[nf * 2 + s], qb[s], sf[nf], 0, 0, 0);
        if (diag) {
#pragma unroll
            for (int nf = 0; nf < 4; nf++)
#pragma unroll
                for (int r = 0; r < 4; r++)
                    if (nf * 16 + g * 4 + r > w * 16 + col) sf[nf][r] = -3e38f;
        }
        // row max (rows are lane-local; combine 4 lane-groups)
        float mt = sf[0][0];
#pragma unroll
        for (int nf = 0; nf < 4; nf++)
#pragma unroll
            for (int r = 0; r < 4; r++) mt = fmaxf(mt, sf[nf][r]);
        mt = fmaxf(mt, __shfl_xor(mt, 16));
        mt = fmaxf(mt, __shfl_xor(mt, 32));
        float mn = fmaxf(mrun, mt);
        float al = __expf(mrun - mn);
        mrun = mn;
        float sum = 0.f;
#pragma unroll
        for (int nf = 0; nf < 4; nf++)
#pragma unroll
            for (int r = 0; r < 4; r++) {
                float pp = __expf(sf[nf][r] - mn);
                sf[nf][r] = pp;
                sum += pp;
            }
        sum += __shfl_xor(sum, 16);
        sum += __shfl_xor(sum, 32);
        lrun = lrun * al + sum;
#pragma unroll
        for (int nf = 0; nf < 4; nf++) acc[nf] *= al;
        // P^T -> P-rows: wave-private swizzled LDS bounce (16B-granular XOR)
#pragma unroll
        for (int nf = 0; nf < 4; nf++) {
            uint2 val;
            val.x = pack_bf16(sf[nf][0], sf[nf][1]);
            val.y = pack_bf16(sf[nf][2], sf[nf][3]);
            *(uint2*)(pbase + ((((nf * 2 + (g >> 1)) ^ sw) << 4) | ((g & 1) << 3))) = val;
        }
#pragma unroll
        for (int s = 0; s < 2; s++) {
            bf16x8 pf = *(const bf16x8*)(pbase + (((s * 4 + g) ^ sw) << 4));
#pragma unroll
            for (int nf = 0; nf < 4; nf++)
                acc[nf] = __builtin_amdgcn_mfma_f32_16x16x32_bf16(VF[nf * 2 + s], pf, acc[nf], 0, 0, 0);
        }
    };

    // software pipeline: K prefetched one tile ahead; V issued at tile start
    issueK(0, KA);
    int j = 0;
    for (;;) {
        issueV(j);
        if (j + 1 < nj) issueK(j + 1, KB);
        tile(KA, j == qt);
        if (j + 1 >= nj) break;
        issueV(j + 1);
        if (j + 2 < nj) issueK(j + 2, KA);
        tile(KB, j + 1 == qt);
        j += 2;
        if (j >= nj) break;
    }

    // epilogue: normalize, transpose via wave-private LDS, coalesced store
    float rinv = __builtin_amdgcn_rcpf(lrun);
#pragma unroll
    for (int nf = 0; nf < 4; nf++)
#pragma unroll
        for (int r = 0; r < 4; r++)
            elds[w][col * 72 + nf * 16 + g * 4 + r] = acc[nf][r] * rinv;
    {
        int ql = lane >> 2, seg = lane & 3;
        size_t orow = (size_t)b * TT + qt * 64 + w * 16 + ql;
#pragma unroll
        for (int p = 0; p < 4; p++) {
            float4 v = *(const float4*)&elds[w][ql * 72 + p * 16 + seg * 4];
            *(float4*)(O + orow * HS + p * 16 + seg * 4) = v;
        }
    }
}

// ---------------------------------------------------------------------------
extern "C" void kernel_launch(void* const* d_in, const int* in_sizes, int n_in,
                              void* d_out, int out_size, void* d_ws, size_t ws_size,
                              hipStream_t stream)
{
    const float* x    = (const float*)d_in[0];
    const float* cosT = (const float*)d_in[1];
    const float* sinT = (const float*)d_in[2];
    const float* Wq   = (const float*)d_in[3];
    const float* Wk   = (const float*)d_in[4];
    const float* Wv   = (const float*)d_in[5];
    float* out = (float*)d_out;

    __bf16* Qb = (__bf16*)d_ws;
    __bf16* Kb = Qb + (size_t)BB * TT * HS;
    __bf16* Vb = Kb + (size_t)BB * TT * HS;   // transposed: [b*64+d][t]
    __bf16* Wt = Vb + (size_t)BB * TT * HS;

    wprep_kernel<<<(192 * 1024) / 256, 256, 0, stream>>>(Wq, Wk, Wv, Wt);
    qkv_rope_kernel<<<(BB * TT) / 64, 256, 0, stream>>>(x, cosT, sinT, Wt, Qb, Kb, Vb);
    attn_kernel<<<dim3(TT / 64 * BB), 256, 0, stream>>>(Qb, Kb, Vb, out);
}